// Round 10
// baseline (69.387 us; speedup 1.0000x reference)
//
#include <hip/hip_runtime.h>
#include <hip/hip_bf16.h>
#include <math.h>

// ---------------------------------------------------------------------------
// memset(2.5KB) + ONE compute kernel (512 blocks x 256 threads, 2 blocks/CU).
// Round-9 lesson: in-kernel flag barrier ~= kernel boundary cost; merging only
// saves the removed kernel's dispatch ramp. So the zeroing node is a trivial
// memset and ALL compute lives in k_mega:
//  P0: Db=|bdw-gdw|,Wb=daw bf16 via AST8 (cross-XCD coherent), minmax
//      partials, S1=|bow-gow|@oaw^T dots, x0b. flags=1.
//  P1: exact-f32 histograms (needs global minmax). flags=2.
//  P2: pu0 GEMM 32x64 tile (BK=64, gl2lds dbuf, XCD-neighborhood swizzle);
//      wait flags>=2 (free, post-GEMM); wg; combine epilogue -> ldsT ->
//      fused h-contribution MFMA -> part2 AST8; blocks 0-15 pu1. flags=3.
//  P3: blocks 0-63 wait flags>=3 -> h=tanh(sum+bdb) -> out=h@pu1^T+bob.
// Entropy path bit-exact f32 (500x amplified by atan).
//
// ws (32-bit words): u32[16..55] bins, u32[64..575] flags (both memset 0);
// f32[1088..1091] bow/gow minmax; f32[2048..4095] minmax slots (lo0 hi0 lo1
// hi1, 512 each); f32[4352..7423] S1; f32[7680..10751] pu1;
// f32[16384..1064959] part2 [16][64][1024].
// bytes: Db @4456448, Wb @6553600, x0b @8650752.
// ---------------------------------------------------------------------------

#define NBINS 10
typedef short bf8v __attribute__((ext_vector_type(8)));
typedef float f32x4 __attribute__((ext_vector_type(4)));
typedef unsigned long long u64;

#define AST(p, v) __hip_atomic_store((p), (v), __ATOMIC_RELAXED, __HIP_MEMORY_SCOPE_AGENT)
#define ALD(p)    __hip_atomic_load((p), __ATOMIC_RELAXED, __HIP_MEMORY_SCOPE_AGENT)

static __device__ __forceinline__ unsigned short f2bf(float f) {
    __hip_bfloat16 h = __float2bfloat16(f);
    return __builtin_bit_cast(unsigned short, h);
}
static __device__ __forceinline__ u64 pack4(float a, float b, float c, float d) {
    return (u64)f2bf(a) | ((u64)f2bf(b) << 16) | ((u64)f2bf(c) << 32) | ((u64)f2bf(d) << 48);
}

#define GL2LDS(gp, lp) __builtin_amdgcn_global_load_lds(                       \
    (__attribute__((address_space(1))) void*)(gp),                             \
    (__attribute__((address_space(3))) void*)(lp), 16, 0, 0)

static __device__ __forceinline__ void stage_slot(const unsigned short* __restrict__ src,
                                                  short* dst, int s, int row0, int k0) {
    int r = s >> 3, g = (s & 7) ^ (r & 7);
    GL2LDS(src + (size_t)(row0 + r) * 1024 + k0 + g * 8, dst + s * 8);
}
static __device__ __forceinline__ bf8v fr(const short* lds, int row, int G) {
    return ((const bf8v*)lds)[row * 8 + (G ^ (row & 7))];
}

static __device__ __forceinline__ float ent_bins(const unsigned* bins, float N) {
    float s = 0.0f;
    for (int b = 0; b < NBINS; b++) {
        float p = __fdiv_rn((float)ALD(&bins[b]), N);
        if (p > 0.0f) s += p * logf(p);
    }
    return -s;
}

__global__ __launch_bounds__(256) void k_mega(
    const float* __restrict__ x, const float* __restrict__ bdw, const float* __restrict__ bdb,
    const float* __restrict__ bow, const float* __restrict__ bob, const float* __restrict__ gdw,
    const float* __restrict__ gow, const float* __restrict__ daw, const float* __restrict__ dab,
    const float* __restrict__ oaw, const float* __restrict__ oab,
    float* __restrict__ out, char* __restrict__ ws) {
    const int blk = blockIdx.x, t = threadIdx.x;
    const int lane = t & 63, wid = t >> 6;
    const int lr = lane & 15, k8 = lane >> 4;
    const int wr = wid >> 1, wc = wid & 1;

    float* ws_f = (float*)ws;
    unsigned* ws_u = (unsigned*)ws;
    unsigned* bins  = ws_u + 16;     // zeroed by memset
    unsigned* flags = ws_u + 64;     // 512, zeroed by memset
    float* slots = ws_f + 2048;      // lo0,hi0,lo1,hi1 x 512
    float* S1    = ws_f + 4352;      // 3x1024
    float* pu1   = ws_f + 7680;      // 3x1024
    float* part2 = ws_f + 16384;     // [16][64][1024]
    unsigned short* Db  = (unsigned short*)(ws + 4456448);
    unsigned short* Wb  = (unsigned short*)(ws + 6553600);
    unsigned short* x0b = (unsigned short*)(ws + 8650752);

    __shared__ short lds_a[2][2048];   // 32x64 bf16
    __shared__ short lds_b[2][4096];   // 64x64 bf16
    __shared__ short ldsT[32 * 72];
    __shared__ float ldsP[64 * 33];
    __shared__ float s_small[16];
    __shared__ unsigned s_hist[NBINS];
    __shared__ float s_wg[2];

    // ===== P0: conv (2 rows of Db & Wb per block) + minmax + S1 + x0b =======
    {
        float lo0 = INFINITY, hi0 = -INFINITY, lo1 = INFINITY, hi1 = -INFINITY;
        int base = blk * 512;  // float4 index of this block's 2-row slice
#pragma unroll
        for (int q = 0; q < 2; q++) {
            int idx = base + q * 256 + t;
            float4 a = ((const float4*)bdw)[idx];
            float4 b = ((const float4*)gdw)[idx];
            float4 w = ((const float4*)daw)[idx];
            lo0 = fminf(lo0, fminf(fminf(a.x, a.y), fminf(a.z, a.w)));
            hi0 = fmaxf(hi0, fmaxf(fmaxf(a.x, a.y), fmaxf(a.z, a.w)));
            lo1 = fminf(lo1, fminf(fminf(b.x, b.y), fminf(b.z, b.w)));
            hi1 = fmaxf(hi1, fmaxf(fmaxf(b.x, b.y), fmaxf(b.z, b.w)));
            AST((u64*)Db + idx, pack4(fabsf(a.x - b.x), fabsf(a.y - b.y),
                                      fabsf(a.z - b.z), fabsf(a.w - b.w)));
            AST((u64*)Wb + idx, pack4(w.x, w.y, w.z, w.w));
        }
        {   // S1: 6 dots per block (3072 total), 32 threads per dot
            int d = t >> 5, kq = t & 31;
            if (d < 6) {
                int g = blk * 6 + d, r = g >> 10, c = g & 1023;
                const float4* bo4 = (const float4*)(bow + r * 1024);
                const float4* go4 = (const float4*)(gow + r * 1024);
                const float4* oa4 = (const float4*)(oaw + c * 1024);
                float s = 0.f;
#pragma unroll
                for (int k4 = kq * 8; k4 < kq * 8 + 8; ++k4) {
                    float4 bv = bo4[k4], gv = go4[k4], wv = oa4[k4];
                    s += fabsf(bv.x - gv.x) * wv.x + fabsf(bv.y - gv.y) * wv.y +
                         fabsf(bv.z - gv.z) * wv.z + fabsf(bv.w - gv.w) * wv.w;
                }
                for (int off = 16; off; off >>= 1) s += __shfl_xor(s, off);
                if (kq == 0) AST(&S1[g], s);
            }
        }
        if (blk < 64) {  // x0b row blk
            float4 v = ((const float4*)(x + (size_t)blk * 524288))[t];
            AST((u64*)x0b + blk * 256 + t, pack4(v.x, v.y, v.z, v.w));
        }
        for (int off = 32; off; off >>= 1) {
            lo0 = fminf(lo0, __shfl_down(lo0, off));
            hi0 = fmaxf(hi0, __shfl_down(hi0, off));
            lo1 = fminf(lo1, __shfl_down(lo1, off));
            hi1 = fmaxf(hi1, __shfl_down(hi1, off));
        }
        if (lane == 0) { s_small[wid] = lo0; s_small[4 + wid] = hi0; s_small[8 + wid] = lo1; s_small[12 + wid] = hi1; }
        __syncthreads();
        if (t == 0) {
            AST(&slots[blk],        fminf(fminf(s_small[0], s_small[1]), fminf(s_small[2], s_small[3])));
            AST(&slots[512 + blk],  fmaxf(fmaxf(s_small[4], s_small[5]), fmaxf(s_small[6], s_small[7])));
            AST(&slots[1024 + blk], fminf(fminf(s_small[8], s_small[9]), fminf(s_small[10], s_small[11])));
            AST(&slots[1536 + blk], fmaxf(fmaxf(s_small[12], s_small[13]), fmaxf(s_small[14], s_small[15])));
        }
        if (blk == 510 || blk == 511) {  // bow/gow minmax
            const float* p = (blk == 510) ? bow : gow;
            float lo = INFINITY, hi = -INFINITY;
#pragma unroll
            for (int q = 0; q < 12; q++) { float v = p[q * 256 + t]; lo = fminf(lo, v); hi = fmaxf(hi, v); }
            for (int off = 32; off; off >>= 1) { lo = fminf(lo, __shfl_down(lo, off)); hi = fmaxf(hi, __shfl_down(hi, off)); }
            __syncthreads();
            if (lane == 0) { s_small[wid] = lo; s_small[4 + wid] = hi; }
            __syncthreads();
            if (t == 0) {
                AST(&ws_f[1088 + 2 * (blk - 510)], fminf(fminf(s_small[0], s_small[1]), fminf(s_small[2], s_small[3])));
                AST(&ws_f[1089 + 2 * (blk - 510)], fmaxf(fmaxf(s_small[4], s_small[5]), fmaxf(s_small[6], s_small[7])));
            }
        }
    }
    __syncthreads();                  // drains AST vmcnt before publish
    if (t == 0) AST(&flags[blk], 1u);
    for (;;) {
        unsigned v0 = ALD(&flags[t]);
        unsigned v1 = ALD(&flags[t + 256]);
        if (__syncthreads_and((int)(v0 >= 1u && v1 >= 1u))) break;
        __builtin_amdgcn_s_sleep(1);
    }

    // ===== P1: histograms (exact f32 bin arithmetic) ========================
    {
        int m, b0, nb;
        if (blk < 240)      { m = 0; b0 = blk;       nb = 240; }
        else if (blk < 480) { m = 1; b0 = blk - 240; nb = 240; }
        else if (blk < 496) { m = 2; b0 = blk - 480; nb = 16; }
        else                { m = 3; b0 = blk - 496; nb = 16; }
        const float* p = (m == 0) ? bdw : (m == 1) ? gdw : (m == 2) ? bow : gow;
        int n = (m < 2) ? 1048576 : 3072;
        float lo, hi;
        if (m < 2) {
            float l = fminf(ALD(&slots[m * 1024 + t]),       ALD(&slots[m * 1024 + 256 + t]));
            float h = fmaxf(ALD(&slots[m * 1024 + 512 + t]), ALD(&slots[m * 1024 + 768 + t]));
            for (int off = 32; off; off >>= 1) { l = fminf(l, __shfl_down(l, off)); h = fmaxf(h, __shfl_down(h, off)); }
            if (lane == 0) { s_small[wid] = l; s_small[4 + wid] = h; }
            __syncthreads();
            lo = fminf(fminf(s_small[0], s_small[1]), fminf(s_small[2], s_small[3]));
            hi = fmaxf(fmaxf(s_small[4], s_small[5]), fmaxf(s_small[6], s_small[7]));
        } else {
            lo = ALD(&ws_f[1088 + 2 * (m - 2)]);
            hi = ALD(&ws_f[1089 + 2 * (m - 2)]);
        }
        float scale = __fdiv_rn(__fsub_rn(hi, lo), 10.0f);
        float lower[NBINS], upper[NBINS];
#pragma unroll
        for (int b = 0; b < NBINS; b++) {
            lower[b] = __fadd_rn(lo, __fmul_rn((float)b, scale));
            upper[b] = __fadd_rn(lower[b], scale);
        }
        unsigned cn[NBINS] = {};
#pragma unroll 4
        for (int i = b0 * 256 + t; i < n; i += nb * 256) {
            float v = p[i];
#pragma unroll
            for (int b = 0; b < NBINS; b++)
                if (v >= lower[b] && v < upper[b]) cn[b]++;
        }
        if (t < NBINS) s_hist[t] = 0;
        __syncthreads();
#pragma unroll
        for (int b = 0; b < NBINS; b++)
            if (cn[b]) atomicAdd(&s_hist[b], cn[b]);
        __syncthreads();
        if (t < NBINS && s_hist[t])
            __hip_atomic_fetch_add(&bins[m * NBINS + t], s_hist[t], __ATOMIC_RELAXED, __HIP_MEMORY_SCOPE_AGENT);
    }
    __syncthreads();
    if (t == 0) AST(&flags[blk], 2u);

    // ===== P2: pu0 GEMM (gl2lds from Db/Wb, XCD-neighborhood swizzle) =======
    const int c8 = blk & 7, rr = blk >> 3;
    const int bi = ((c8 >> 1) << 3) | (rr >> 3);   // 0..31
    const int bj = ((c8 & 1) << 3) | (rr & 7);     // 0..15
    f32x4 acc0 = {0.f, 0.f, 0.f, 0.f}, acc1 = {0.f, 0.f, 0.f, 0.f};
    {
        stage_slot(Db, lds_a[0], t, bi * 32, 0);
        stage_slot(Wb, lds_b[0], t, bj * 64, 0);
        stage_slot(Wb, lds_b[0], t + 256, bj * 64, 0);
        int cur = 0;
        for (int tt = 0; tt < 16; ++tt) {
            __syncthreads();
            if (tt + 1 < 16) {
                int k0 = (tt + 1) * 64;
                stage_slot(Db, lds_a[cur ^ 1], t, bi * 32, k0);
                stage_slot(Wb, lds_b[cur ^ 1], t, bj * 64, k0);
                stage_slot(Wb, lds_b[cur ^ 1], t + 256, bj * 64, k0);
            }
#pragma unroll
            for (int kk = 0; kk < 2; kk++) {
                bf8v a  = fr(lds_a[cur], wr * 16 + lr, kk * 4 + k8);
                bf8v b0 = fr(lds_b[cur], wc * 32 + lr, kk * 4 + k8);
                bf8v b1 = fr(lds_b[cur], wc * 32 + 16 + lr, kk * 4 + k8);
                acc0 = __builtin_amdgcn_mfma_f32_16x16x32_bf16(a, b0, acc0, 0, 0, 0);
                acc1 = __builtin_amdgcn_mfma_f32_16x16x32_bf16(a, b1, acc1, 0, 0, 0);
            }
            cur ^= 1;
        }
    }

    // ---- wait flags>=2 (hist long done), compute wg ----
    for (;;) {
        unsigned v0 = ALD(&flags[t]);
        unsigned v1 = ALD(&flags[t + 256]);
        if (__syncthreads_and((int)(v0 >= 2u && v1 >= 2u))) break;
        __builtin_amdgcn_s_sleep(1);
    }
    if (t == 0) {
        float e0 = ent_bins(&bins[0], 1048576.0f);
        float e1 = ent_bins(&bins[10], 1048576.0f);
        float e2 = ent_bins(&bins[20], 3072.0f);
        float e3 = ent_bins(&bins[30], 3072.0f);
        const float API = (float)(0.4 / M_PI);
        s_wg[0] = API * atanf(500.0f * (e0 - e1)) + 0.5f;
        s_wg[1] = API * atanf(500.0f * (e2 - e3)) + 0.5f;
    }
    __syncthreads();

    // ---- combine epilogue -> ldsT; fused h-contribution; part2 AST8 ----
    {
        float wg = s_wg[0];
#pragma unroll
        for (int j = 0; j < 2; j++) {
            f32x4 a = j ? acc1 : acc0;
#pragma unroll
            for (int r = 0; r < 4; r++) {
                int il = wr * 16 + k8 * 4 + r;
                int jl = wc * 32 + j * 16 + lr;
                int ig = bi * 32 + il, jg = bj * 64 + jl;
                float s = a[r] + dab[jg];
                float wl = 1.0f / (1.0f + expf(-s));
                float w = wg * wl + (1.0f - wg);
                float o = bdw[ig * 1024 + jg] * w + gdw[ig * 1024 + jg] * (1.0f - w);
                ldsT[il * 72 + jl] = (short)f2bf(o);
            }
        }
        __syncthreads();
        f32x4 ah0 = {0.f, 0.f, 0.f, 0.f}, ah1 = {0.f, 0.f, 0.f, 0.f};
#pragma unroll
        for (int ks = 0; ks < 2; ks++) {
            int cl = wc * 16 + lr;
            bf8v b = *(const bf8v*)&ldsT[cl * 72 + ks * 32 + k8 * 8];
            bf8v a0 = *(const bf8v*)&x0b[(wr * 32 + lr) * 1024 + bj * 64 + ks * 32 + k8 * 8];
            bf8v a1 = *(const bf8v*)&x0b[(wr * 32 + 16 + lr) * 1024 + bj * 64 + ks * 32 + k8 * 8];
            ah0 = __builtin_amdgcn_mfma_f32_16x16x32_bf16(a0, b, ah0, 0, 0, 0);
            ah1 = __builtin_amdgcn_mfma_f32_16x16x32_bf16(a1, b, ah1, 0, 0, 0);
        }
#pragma unroll
        for (int mi = 0; mi < 2; mi++) {
            f32x4 ah = mi ? ah1 : ah0;
#pragma unroll
            for (int r = 0; r < 4; r++)
                ldsP[(wr * 32 + mi * 16 + k8 * 4 + r) * 33 + wc * 16 + lr] = ah[r];
        }
        __syncthreads();
        {
            int m = t >> 2, c0 = (t & 3) * 8;
            const float* row = &ldsP[m * 33 + c0];
            float* gp = part2 + ((size_t)(bj * 64 + m) << 10) + bi * 32 + c0;
#pragma unroll
            for (int q = 0; q < 4; q++) {
                u64 u = ((u64)__float_as_uint(row[2 * q + 1]) << 32) | __float_as_uint(row[2 * q]);
                AST((u64*)(gp + 2 * q), u);
            }
        }
    }
    if (blk < 16 && t < 192) {  // pu1 combine
        int r = t >> 6, c = blk * 64 + (t & 63);
        float s1 = ALD(&S1[r * 1024 + c]);
        float wl = 1.0f / (1.0f + expf(-(s1 + oab[c])));
        float wg = s_wg[1];
        float w = wg * wl + (1.0f - wg);
        AST(&pu1[r * 1024 + c], bow[r * 1024 + c] * w + gow[r * 1024 + c] * (1.0f - w));
    }
    __syncthreads();           // drains AST stores before flag publish
    if (t == 0) AST(&flags[blk], 3u);

    // ===== P3: blocks 0-63: h = tanh(.); out = h @ pu1^T + bob ==============
    if (blk < 64) {
        for (;;) {
            unsigned v0 = ALD(&flags[t]);
            unsigned v1 = ALD(&flags[t + 256]);
            if (__syncthreads_and((int)(v0 >= 3u && v1 >= 3u))) break;
            __builtin_amdgcn_s_sleep(1);
        }
        const int m = blk, c0 = t * 4;
        float s0 = 0, s1 = 0, s2 = 0, s3 = 0;
#pragma unroll
        for (int b = 0; b < 16; b++) {
            const float* pp = part2 + ((size_t)(b * 64 + m) << 10) + c0;
            u64 u0 = ALD((const u64*)pp);
            u64 u1 = ALD((const u64*)(pp + 2));
            s0 += __uint_as_float((unsigned)u0); s1 += __uint_as_float((unsigned)(u0 >> 32));
            s2 += __uint_as_float((unsigned)u1); s3 += __uint_as_float((unsigned)(u1 >> 32));
        }
        float h0 = tanhf(s0 + bdb[c0]);
        float h1 = tanhf(s1 + bdb[c0 + 1]);
        float h2 = tanhf(s2 + bdb[c0 + 2]);
        float h3 = tanhf(s3 + bdb[c0 + 3]);
        float p0, p1, p2;
        {
            u64 a0 = ALD((const u64*)(pu1 + c0)),        a1 = ALD((const u64*)(pu1 + c0 + 2));
            u64 b0 = ALD((const u64*)(pu1 + 1024 + c0)), b1 = ALD((const u64*)(pu1 + 1024 + c0 + 2));
            u64 d0 = ALD((const u64*)(pu1 + 2048 + c0)), d1 = ALD((const u64*)(pu1 + 2048 + c0 + 2));
            p0 = h0 * __uint_as_float((unsigned)a0) + h1 * __uint_as_float((unsigned)(a0 >> 32)) +
                 h2 * __uint_as_float((unsigned)a1) + h3 * __uint_as_float((unsigned)(a1 >> 32));
            p1 = h0 * __uint_as_float((unsigned)b0) + h1 * __uint_as_float((unsigned)(b0 >> 32)) +
                 h2 * __uint_as_float((unsigned)b1) + h3 * __uint_as_float((unsigned)(b1 >> 32));
            p2 = h0 * __uint_as_float((unsigned)d0) + h1 * __uint_as_float((unsigned)(d0 >> 32)) +
                 h2 * __uint_as_float((unsigned)d1) + h3 * __uint_as_float((unsigned)(d1 >> 32));
        }
        for (int off = 32; off; off >>= 1) {
            p0 += __shfl_down(p0, off);
            p1 += __shfl_down(p1, off);
            p2 += __shfl_down(p2, off);
        }
        if (lane == 0) { s_small[wid] = p0; s_small[4 + wid] = p1; s_small[8 + wid] = p2; }
        __syncthreads();
        if (t == 0) {
            out[m * 3 + 0] = s_small[0] + s_small[1] + s_small[2] + s_small[3] + bob[0];
            out[m * 3 + 1] = s_small[4] + s_small[5] + s_small[6] + s_small[7] + bob[1];
            out[m * 3 + 2] = s_small[8] + s_small[9] + s_small[10] + s_small[11] + bob[2];
        }
    }
}

extern "C" void kernel_launch(void* const* d_in, const int* in_sizes, int n_in,
                              void* d_out, int out_size, void* d_ws, size_t ws_size,
                              hipStream_t stream) {
    const float* x   = (const float*)d_in[0];
    const float* bdw = (const float*)d_in[1];
    const float* bdb = (const float*)d_in[2];
    const float* bow = (const float*)d_in[3];
    const float* bob = (const float*)d_in[4];
    const float* gdw = (const float*)d_in[5];
    const float* gow = (const float*)d_in[6];
    const float* daw = (const float*)d_in[7];
    const float* dab = (const float*)d_in[8];
    const float* oaw = (const float*)d_in[9];
    const float* oab = (const float*)d_in[10];
    float* out = (float*)d_out;
    char* ws = (char*)d_ws;

    // zero words 0..639: bins (16..55) + flags (64..575)
    hipMemsetAsync(d_ws, 0, 2560, stream);
    k_mega<<<512, 256, 0, stream>>>(x, bdw, bdb, bow, bob, gdw, gow, daw, dab,
                                    oaw, oab, out, ws);
}

// Round 11
// 54.905 us; speedup vs baseline: 1.2638x; 1.2638x over previous
//
#include <hip/hip_runtime.h>
#include <hip/hip_bf16.h>
#include <math.h>

// ---------------------------------------------------------------------------
// FINAL: 3-kernel chain (measured optimum of the structural space).
// Node-count ledger (measured): 10 nodes=155us, 3=55.3, 2=57.1, 1(+memset)=69.4.
// Kernel boundaries are the cheapest bulk-coherence primitive on MI355X:
//  - cg::grid.sync / threadfence = L2 writeback+invalidate walks (~30us, R4)
//  - same-address atomic barrier = serialized RMWs (~15-20us, R5)
//  - flag-array barrier ~ node cost, but bulk data must then go through
//    agent-scope atomics which defeat L2 for the consumer (R9/R10).
//
// K1 k_prep (512): Db=|bdw-gdw| bf16, Wb=daw bf16, x0b, minmax partials,
//    S1=|bow-gow|@oaw^T partial dots, zero flags+bins. Plain cached stores.
// K2 k_main (512, 2 blocks/CU): exact-f32 histograms -> flag; pu0 GEMM
//    32x64-tile (BK=64, gl2lds double-buffer, XCD-neighborhood swizzle:
//    per-XCD panels L2-resident); flag-wait (hidden behind GEMM); wg;
//    combine epilogue -> ldsT -> fused h-contribution MFMA -> part2.
//    Blocks 0-15: pu1 combine.
// K3 k_out (64): h = tanh(sum part2 + bdb); out = h @ pu1^T + bob.
// Entropy path bit-exact f32 (500x amplified by atan).
//
// ws (f32 words): [8..11] bow/gow minmax; u32[16..55] bins; u32[64..575]
// flags(512); [576..1599] minmax slots 4x256; [1600..4671] S1; [4736..7807]
// pu1; [8192..1056767] part2 [16][64][1024].
// bytes: Db @4227072, Wb @6324224, x0b @8421376.
// ---------------------------------------------------------------------------

#define NBINS 10
typedef short bf8v __attribute__((ext_vector_type(8)));
typedef float f32x4 __attribute__((ext_vector_type(4)));

#define AST(p, v) __hip_atomic_store((p), (v), __ATOMIC_RELAXED, __HIP_MEMORY_SCOPE_AGENT)
#define ALD(p)    __hip_atomic_load((p), __ATOMIC_RELAXED, __HIP_MEMORY_SCOPE_AGENT)

static __device__ __forceinline__ unsigned short f2bf(float f) {
    __hip_bfloat16 h = __float2bfloat16(f);
    return __builtin_bit_cast(unsigned short, h);
}

#define GL2LDS(gp, lp) __builtin_amdgcn_global_load_lds(                       \
    (__attribute__((address_space(1))) void*)(gp),                             \
    (__attribute__((address_space(3))) void*)(lp), 16, 0, 0)

// Stage one 16B slot per thread: slot s -> row s>>3, k-group (s&7)^(row&7)
// (XOR swizzle on the GLOBAL source; LDS stays linear per gl2lds rules).
static __device__ __forceinline__ void stage_slot(const unsigned short* __restrict__ src,
                                                  short* dst, int s, int row0, int k0) {
    int r = s >> 3, g = (s & 7) ^ (r & 7);
    GL2LDS(src + (size_t)(row0 + r) * 1024 + k0 + g * 8, dst + s * 8);
}
// Fragment read: global k-group G of row -> slot G^(row&7)
static __device__ __forceinline__ bf8v fr(const short* lds, int row, int G) {
    return ((const bf8v*)lds)[row * 8 + (G ^ (row & 7))];
}

static __device__ __forceinline__ float ent_bins(const unsigned* bins, float N) {
    float s = 0.0f;
    for (int b = 0; b < NBINS; b++) {
        float p = __fdiv_rn((float)ALD(&bins[b]), N);
        if (p > 0.0f) s += p * logf(p);
    }
    return -s;
}

// =============================== K1 =========================================
__global__ __launch_bounds__(256) void k_prep(
    const float* __restrict__ x, const float* __restrict__ bdw, const float* __restrict__ bow,
    const float* __restrict__ gdw, const float* __restrict__ gow, const float* __restrict__ daw,
    const float* __restrict__ oaw, char* __restrict__ ws) {
    const int blk = blockIdx.x, t = threadIdx.x;
    const int lane = t & 63, wid = t >> 6;
    float* ws_f = (float*)ws;
    unsigned* ws_u = (unsigned*)ws;
    float* slots = ws_f + 576;
    float* S1    = ws_f + 1600;
    unsigned short* Db  = (unsigned short*)(ws + 4227072);
    unsigned short* Wb  = (unsigned short*)(ws + 6324224);
    unsigned short* x0b = (unsigned short*)(ws + 8421376);
    __shared__ float sp[256];
    __shared__ float s_small[16];

    if (blk < 256) {
        float lo0 = INFINITY, hi0 = -INFINITY, lo1 = INFINITY, hi1 = -INFINITY;
        int fbase = blk * 1024 + t;
#pragma unroll
        for (int q = 0; q < 4; q++) {
            int idx = fbase + q * 256;
            float4 a = ((const float4*)bdw)[idx];
            float4 b = ((const float4*)gdw)[idx];
            float4 w = ((const float4*)daw)[idx];
            lo0 = fminf(lo0, fminf(fminf(a.x, a.y), fminf(a.z, a.w)));
            hi0 = fmaxf(hi0, fmaxf(fmaxf(a.x, a.y), fmaxf(a.z, a.w)));
            lo1 = fminf(lo1, fminf(fminf(b.x, b.y), fminf(b.z, b.w)));
            hi1 = fmaxf(hi1, fmaxf(fmaxf(b.x, b.y), fmaxf(b.z, b.w)));
            ushort4 d, ww;
            d.x = f2bf(fabsf(a.x - b.x)); d.y = f2bf(fabsf(a.y - b.y));
            d.z = f2bf(fabsf(a.z - b.z)); d.w = f2bf(fabsf(a.w - b.w));
            ww.x = f2bf(w.x); ww.y = f2bf(w.y); ww.z = f2bf(w.z); ww.w = f2bf(w.w);
            ((ushort4*)Db)[idx] = d;
            ((ushort4*)Wb)[idx] = ww;
        }
        for (int off = 32; off; off >>= 1) {
            lo0 = fminf(lo0, __shfl_down(lo0, off));
            hi0 = fmaxf(hi0, __shfl_down(hi0, off));
            lo1 = fminf(lo1, __shfl_down(lo1, off));
            hi1 = fmaxf(hi1, __shfl_down(hi1, off));
        }
        if (lane == 0) { s_small[wid] = lo0; s_small[4 + wid] = hi0; s_small[8 + wid] = lo1; s_small[12 + wid] = hi1; }
        __syncthreads();
        if (t == 0) {
            slots[blk]       = fminf(fminf(s_small[0], s_small[1]), fminf(s_small[2], s_small[3]));
            slots[256 + blk] = fmaxf(fmaxf(s_small[4], s_small[5]), fmaxf(s_small[6], s_small[7]));
            slots[512 + blk] = fminf(fminf(s_small[8], s_small[9]), fminf(s_small[10], s_small[11]));
            slots[768 + blk] = fmaxf(fmaxf(s_small[12], s_small[13]), fmaxf(s_small[14], s_small[15]));
        }
    } else {
        const int blk2 = blk - 256;
        {   // S1 partial dots: 12 dots per block
            int d = t >> 4, kq = t & 15;
            if (d < 12) {
                int r = d >> 2, c = blk2 * 4 + (d & 3);
                const float4* bo4 = (const float4*)(bow + r * 1024);
                const float4* go4 = (const float4*)(gow + r * 1024);
                const float4* oa4 = (const float4*)(oaw + c * 1024);
                float s = 0.f;
#pragma unroll
                for (int k4 = kq * 16; k4 < kq * 16 + 16; ++k4) {
                    float4 bv = bo4[k4], gv = go4[k4], wv = oa4[k4];
                    s += fabsf(bv.x - gv.x) * wv.x + fabsf(bv.y - gv.y) * wv.y +
                         fabsf(bv.z - gv.z) * wv.z + fabsf(bv.w - gv.w) * wv.w;
                }
                sp[t] = s;
            }
            __syncthreads();
            if (t < 12) {
                float s = 0.f;
#pragma unroll
                for (int q = 0; q < 16; q++) s += sp[t * 16 + q];
                S1[(t >> 2) * 1024 + blk2 * 4 + (t & 3)] = s;
            }
        }
        if (blk == 256 || blk == 257) {  // bow/gow minmax
            const float* p = (blk == 256) ? bow : gow;
            float lo = INFINITY, hi = -INFINITY;
#pragma unroll
            for (int q = 0; q < 12; q++) { float v = p[q * 256 + t]; lo = fminf(lo, v); hi = fmaxf(hi, v); }
            for (int off = 32; off; off >>= 1) { lo = fminf(lo, __shfl_down(lo, off)); hi = fmaxf(hi, __shfl_down(hi, off)); }
            __syncthreads();
            if (lane == 0) { s_small[wid] = lo; s_small[4 + wid] = hi; }
            __syncthreads();
            if (t == 0) {
                ws_f[8 + 2 * (blk - 256)] = fminf(fminf(s_small[0], s_small[1]), fminf(s_small[2], s_small[3]));
                ws_f[9 + 2 * (blk - 256)] = fmaxf(fmaxf(s_small[4], s_small[5]), fmaxf(s_small[6], s_small[7]));
            }
        }
        if (blk == 258) {  // zero flags(512) + bins(40)
            ws_u[64 + t] = 0u;
            ws_u[320 + t] = 0u;
            if (t < 40) ws_u[16 + t] = 0u;
        }
        if (blk >= 260 && blk < 324) {  // x0b rows
            int row = blk - 260;
            float4 v = ((const float4*)(x + (size_t)row * 524288))[t];
            ushort4 o; o.x = f2bf(v.x); o.y = f2bf(v.y); o.z = f2bf(v.z); o.w = f2bf(v.w);
            ((ushort4*)x0b)[row * 256 + t] = o;
        }
    }
}

// =============================== K2 =========================================
__global__ __launch_bounds__(256) void k_main(
    const float* __restrict__ bdw, const float* __restrict__ gdw, const float* __restrict__ dab,
    const float* __restrict__ bow, const float* __restrict__ gow, const float* __restrict__ oab,
    char* __restrict__ ws) {
    const int blk = blockIdx.x, t = threadIdx.x;
    const int lane = t & 63, wid = t >> 6;
    const int lr = lane & 15, k8 = lane >> 4;
    const int wr = wid >> 1, wc = wid & 1;

    float* ws_f = (float*)ws;
    unsigned* ws_u = (unsigned*)ws;
    unsigned* bins  = ws_u + 16;
    unsigned* flags = ws_u + 64;
    float* slots = ws_f + 576;
    float* S1    = ws_f + 1600;
    float* pu1   = ws_f + 4736;
    float* part2 = ws_f + 8192;
    const unsigned short* Db  = (const unsigned short*)(ws + 4227072);
    const unsigned short* Wb  = (const unsigned short*)(ws + 6324224);
    const unsigned short* x0b = (const unsigned short*)(ws + 8421376);

    __shared__ short lds_a[2][2048];   // 32x64 bf16
    __shared__ short lds_b[2][4096];   // 64x64 bf16
    __shared__ short ldsT[32 * 72];
    __shared__ float s_small[16];
    __shared__ unsigned s_hist[NBINS];
    __shared__ float s_wg[2];

    // ---- histograms (exact f32 bin arithmetic) ----
    {
        int m, b0, nb;
        if (blk < 240)      { m = 0; b0 = blk;       nb = 240; }
        else if (blk < 480) { m = 1; b0 = blk - 240; nb = 240; }
        else if (blk < 496) { m = 2; b0 = blk - 480; nb = 16; }
        else                { m = 3; b0 = blk - 496; nb = 16; }
        const float* p = (m == 0) ? bdw : (m == 1) ? gdw : (m == 2) ? bow : gow;
        int n = (m < 2) ? 1048576 : 3072;
        float lo, hi;
        if (m < 2) {
            float l = slots[m * 512 + t];
            float h = slots[m * 512 + 256 + t];
            for (int off = 32; off; off >>= 1) { l = fminf(l, __shfl_down(l, off)); h = fmaxf(h, __shfl_down(h, off)); }
            if (lane == 0) { s_small[wid] = l; s_small[4 + wid] = h; }
            __syncthreads();
            lo = fminf(fminf(s_small[0], s_small[1]), fminf(s_small[2], s_small[3]));
            hi = fmaxf(fmaxf(s_small[4], s_small[5]), fmaxf(s_small[6], s_small[7]));
        } else {
            lo = ws_f[8 + 2 * (m - 2)];
            hi = ws_f[9 + 2 * (m - 2)];
        }
        float scale = __fdiv_rn(__fsub_rn(hi, lo), 10.0f);
        float lower[NBINS], upper[NBINS];
#pragma unroll
        for (int b = 0; b < NBINS; b++) {
            lower[b] = __fadd_rn(lo, __fmul_rn((float)b, scale));
            upper[b] = __fadd_rn(lower[b], scale);
        }
        unsigned cn[NBINS] = {};
#pragma unroll 4
        for (int i = b0 * 256 + t; i < n; i += nb * 256) {
            float v = p[i];
#pragma unroll
            for (int b = 0; b < NBINS; b++)
                if (v >= lower[b] && v < upper[b]) cn[b]++;
        }
        if (t < NBINS) s_hist[t] = 0;
        __syncthreads();
#pragma unroll
        for (int b = 0; b < NBINS; b++)
            if (cn[b]) atomicAdd(&s_hist[b], cn[b]);
        __syncthreads();
        if (t < NBINS && s_hist[t])
            __hip_atomic_fetch_add(&bins[m * NBINS + t], s_hist[t], __ATOMIC_RELAXED, __HIP_MEMORY_SCOPE_AGENT);
    }
    __syncthreads();
    if (t == 0) AST(&flags[blk], 1u);

    // ---- pu0 GEMM: 32x64 tile, BK=64, XCD-neighborhood swizzle ----
    // XCD c=blk&7 owns bi in [(c>>1)*8, +8) x bj in [(c&1)*8, +8):
    // A 8x64KB + B 8x128KB = 1.5MB -> L2-resident per XCD.
    const int c8 = blk & 7, rr = blk >> 3;
    const int bi = ((c8 >> 1) << 3) | (rr >> 3);   // 0..31
    const int bj = ((c8 & 1) << 3) | (rr & 7);     // 0..15
    f32x4 acc0 = {0.f, 0.f, 0.f, 0.f}, acc1 = {0.f, 0.f, 0.f, 0.f};
    {
        stage_slot(Db, lds_a[0], t, bi * 32, 0);
        stage_slot(Wb, lds_b[0], t, bj * 64, 0);
        stage_slot(Wb, lds_b[0], t + 256, bj * 64, 0);
        int cur = 0;
        for (int tt = 0; tt < 16; ++tt) {
            __syncthreads();  // all waves' gl2lds drained -> buffer cur ready
            if (tt + 1 < 16) {
                int k0 = (tt + 1) * 64;
                stage_slot(Db, lds_a[cur ^ 1], t, bi * 32, k0);
                stage_slot(Wb, lds_b[cur ^ 1], t, bj * 64, k0);
                stage_slot(Wb, lds_b[cur ^ 1], t + 256, bj * 64, k0);
            }
#pragma unroll
            for (int kk = 0; kk < 2; kk++) {
                bf8v a  = fr(lds_a[cur], wr * 16 + lr, kk * 4 + k8);
                bf8v b0 = fr(lds_b[cur], wc * 32 + lr, kk * 4 + k8);
                bf8v b1 = fr(lds_b[cur], wc * 32 + 16 + lr, kk * 4 + k8);
                acc0 = __builtin_amdgcn_mfma_f32_16x16x32_bf16(a, b0, acc0, 0, 0, 0);
                acc1 = __builtin_amdgcn_mfma_f32_16x16x32_bf16(a, b1, acc1, 0, 0, 0);
            }
            cur ^= 1;
        }
    }

    // ---- wait for histograms (done long ago), compute wg ----
    for (;;) {
        unsigned v0 = ALD(&flags[t]);
        unsigned v1 = ALD(&flags[t + 256]);
        if (__syncthreads_and((int)(v0 >= 1u && v1 >= 1u))) break;
        __builtin_amdgcn_s_sleep(1);
    }
    if (t == 0) {
        float e0 = ent_bins(&bins[0], 1048576.0f);
        float e1 = ent_bins(&bins[10], 1048576.0f);
        float e2 = ent_bins(&bins[20], 3072.0f);
        float e3 = ent_bins(&bins[30], 3072.0f);
        const float API = (float)(0.4 / M_PI);
        s_wg[0] = API * atanf(500.0f * (e0 - e1)) + 0.5f;
        s_wg[1] = API * atanf(500.0f * (e2 - e3)) + 0.5f;
    }
    __syncthreads();

    // ---- combine epilogue -> transposed bf16 tile in LDS ----
    {
        float wg = s_wg[0];
#pragma unroll
        for (int j = 0; j < 2; j++) {
            f32x4 a = j ? acc1 : acc0;
#pragma unroll
            for (int r = 0; r < 4; r++) {
                int il = wr * 16 + k8 * 4 + r;
                int jl = wc * 32 + j * 16 + lr;
                int ig = bi * 32 + il, jg = bj * 64 + jl;
                float s = a[r] + dab[jg];
                float wl = 1.0f / (1.0f + expf(-s));
                float w = wg * wl + (1.0f - wg);
                float o = bdw[ig * 1024 + jg] * w + gdw[ig * 1024 + jg] * (1.0f - w);
                ldsT[il * 72 + jl] = (short)f2bf(o);
            }
        }
        __syncthreads();
        // fused h-contribution: part2[bj][m 0..63][bi-panel c 0..31]
        f32x4 ah0 = {0.f, 0.f, 0.f, 0.f}, ah1 = {0.f, 0.f, 0.f, 0.f};
#pragma unroll
        for (int ks = 0; ks < 2; ks++) {
            int cl = wc * 16 + lr;
            bf8v b = *(const bf8v*)&ldsT[cl * 72 + ks * 32 + k8 * 8];
            bf8v a0 = *(const bf8v*)&x0b[(wr * 32 + lr) * 1024 + bj * 64 + ks * 32 + k8 * 8];
            bf8v a1 = *(const bf8v*)&x0b[(wr * 32 + 16 + lr) * 1024 + bj * 64 + ks * 32 + k8 * 8];
            ah0 = __builtin_amdgcn_mfma_f32_16x16x32_bf16(a0, b, ah0, 0, 0, 0);
            ah1 = __builtin_amdgcn_mfma_f32_16x16x32_bf16(a1, b, ah1, 0, 0, 0);
        }
#pragma unroll
        for (int mi = 0; mi < 2; mi++) {
            f32x4 ah = mi ? ah1 : ah0;
#pragma unroll
            for (int r = 0; r < 4; r++) {
                int m = wr * 32 + mi * 16 + k8 * 4 + r;
                int cg = bi * 32 + wc * 16 + lr;
                part2[((size_t)(bj * 64 + m) << 10) + cg] = ah[r];
            }
        }
    }
    if (blk < 16 && t < 192) {  // pu1 combine
        int r = t >> 6, c = blk * 64 + (t & 63);
        float s1 = S1[r * 1024 + c];
        float wl = 1.0f / (1.0f + expf(-(s1 + oab[c])));
        float wg = s_wg[1];
        float w = wg * wl + (1.0f - wg);
        pu1[r * 1024 + c] = bow[r * 1024 + c] * w + gow[r * 1024 + c] * (1.0f - w);
    }
}

// =============================== K3 =========================================
__global__ __launch_bounds__(256) void k_out(
    const float* __restrict__ bdb, const float* __restrict__ bob,
    float* __restrict__ out, const char* __restrict__ ws) {
    const int m = blockIdx.x, t = threadIdx.x;
    const int lane = t & 63, wid = t >> 6;
    const float* ws_f = (const float*)ws;
    const float* pu1   = ws_f + 4736;
    const float* part2 = ws_f + 8192;
    __shared__ float s_small[16];

    const int c0 = t * 4;
    f32x4 s = {0.f, 0.f, 0.f, 0.f};
#pragma unroll
    for (int b = 0; b < 16; b++)
        s += *(const f32x4*)(part2 + ((size_t)(b * 64 + m) << 10) + c0);
    float h0 = tanhf(s[0] + bdb[c0]);
    float h1 = tanhf(s[1] + bdb[c0 + 1]);
    float h2 = tanhf(s[2] + bdb[c0 + 2]);
    float h3 = tanhf(s[3] + bdb[c0 + 3]);
    float p0, p1, p2;
    {
        f32x4 q0 = *(const f32x4*)(pu1 + c0);
        f32x4 q1 = *(const f32x4*)(pu1 + 1024 + c0);
        f32x4 q2 = *(const f32x4*)(pu1 + 2048 + c0);
        p0 = h0 * q0[0] + h1 * q0[1] + h2 * q0[2] + h3 * q0[3];
        p1 = h0 * q1[0] + h1 * q1[1] + h2 * q1[2] + h3 * q1[3];
        p2 = h0 * q2[0] + h1 * q2[1] + h2 * q2[2] + h3 * q2[3];
    }
    for (int off = 32; off; off >>= 1) {
        p0 += __shfl_down(p0, off);
        p1 += __shfl_down(p1, off);
        p2 += __shfl_down(p2, off);
    }
    if (lane == 0) { s_small[wid] = p0; s_small[4 + wid] = p1; s_small[8 + wid] = p2; }
    __syncthreads();
    if (t == 0) {
        out[m * 3 + 0] = s_small[0] + s_small[1] + s_small[2] + s_small[3] + bob[0];
        out[m * 3 + 1] = s_small[4] + s_small[5] + s_small[6] + s_small[7] + bob[1];
        out[m * 3 + 2] = s_small[8] + s_small[9] + s_small[10] + s_small[11] + bob[2];
    }
}

extern "C" void kernel_launch(void* const* d_in, const int* in_sizes, int n_in,
                              void* d_out, int out_size, void* d_ws, size_t ws_size,
                              hipStream_t stream) {
    const float* x   = (const float*)d_in[0];
    const float* bdw = (const float*)d_in[1];
    const float* bdb = (const float*)d_in[2];
    const float* bow = (const float*)d_in[3];
    const float* bob = (const float*)d_in[4];
    const float* gdw = (const float*)d_in[5];
    const float* gow = (const float*)d_in[6];
    const float* daw = (const float*)d_in[7];
    const float* dab = (const float*)d_in[8];
    const float* oaw = (const float*)d_in[9];
    const float* oab = (const float*)d_in[10];
    float* out = (float*)d_out;
    char* ws = (char*)d_ws;

    k_prep<<<512, 256, 0, stream>>>(x, bdw, bow, gdw, gow, daw, oaw, ws);
    k_main<<<512, 256, 0, stream>>>(bdw, gdw, dab, bow, gow, oab, ws);
    k_out<<<64, 256, 0, stream>>>(bdb, bob, out, ws);
}